// Round 9
// baseline (199.782 us; speedup 1.0000x reference)
//
#include <hip/hip_runtime.h>

#define IN_C 128
#define OUT_C 256
#define LN_EPS 1e-5f
#define SCAN_BLK 1024

typedef __attribute__((ext_vector_type(8))) short bf16x8;
typedef __attribute__((ext_vector_type(4))) float f32x4;

__device__ __forceinline__ unsigned int f2bf(float f) {
    unsigned int u = __float_as_uint(f);
    return (u + 0x7fffu + ((u >> 16) & 1u)) >> 16;   // RNE
}
__device__ __forceinline__ float bf_lo(unsigned int p) { return __uint_as_float(p << 16); }
__device__ __forceinline__ float bf_hi(unsigned int p) { return __uint_as_float(p & 0xffff0000u); }

// ---------- zero cursor ----------
__global__ __launch_bounds__(256) void k_zero(int4* __restrict__ p, int n4) {
    int i = blockIdx.x * 256 + threadIdx.x;
    if (i < n4) p[i] = (int4){0, 0, 0, 0};
}

// ---------- fused: slot reservation (atomics) + x->bf16 convert + weight fragments ----------
__global__ __launch_bounds__(256) void k_slotcvt(const int* __restrict__ col,
                                                 int* __restrict__ cursor,
                                                 unsigned short* __restrict__ slot,
                                                 const float* __restrict__ x,
                                                 unsigned short* __restrict__ x_bf,
                                                 const float* __restrict__ Wg,
                                                 const float* __restrict__ Wr,
                                                 unsigned short* __restrict__ wgf,
                                                 unsigned short* __restrict__ wrf,
                                                 int E, int ncvt) {
    int i = blockIdx.x * 256 + threadIdx.x;

    // --- slot: 4 edges/thread (atomics issued first, long latency) ---
    int base = i * 4;
    unsigned int s0, s1, s2, s3;
    bool full = (base + 4 <= E);
    if (full) {
        int4 c = *reinterpret_cast<const int4*>(col + base);
        s0 = (unsigned int)atomicAdd(&cursor[c.x], 1);
        s1 = (unsigned int)atomicAdd(&cursor[c.y], 1);
        s2 = (unsigned int)atomicAdd(&cursor[c.z], 1);
        s3 = (unsigned int)atomicAdd(&cursor[c.w], 1);
    } else {
        for (int e = base; e < E; ++e)
            slot[e] = (unsigned short)atomicAdd(&cursor[col[e]], 1);
    }

    // --- x -> bf16 (unscaled), 32 floats per thread ---
    if (i < ncvt) {
        const float4* xv = reinterpret_cast<const float4*>(x) + (size_t)i * 8;
        uint4* dst = reinterpret_cast<uint4*>(x_bf) + (size_t)i * 4;
#pragma unroll
        for (int j = 0; j < 4; ++j) {
            float4 a = xv[j * 2], b = xv[j * 2 + 1];
            uint4 o;
            o.x = f2bf(a.x) | (f2bf(a.y) << 16);
            o.y = f2bf(a.z) | (f2bf(a.w) << 16);
            o.z = f2bf(b.x) | (f2bf(b.y) << 16);
            o.w = f2bf(b.z) | (f2bf(b.w) << 16);
            dst[j] = o;
        }
    }

    // --- weight fragments (first 8192 threads) ---
    if (i < 8192) {
        int wsel = i >> 12;
        int u = i & 4095;
        int ct = u >> 8, kt = (u >> 6) & 3, l = u & 63;
        int k0 = kt * 32 + (l >> 4) * 8;
        int colw = ct * 16 + (l & 15);
        const float* W = wsel ? Wr : Wg;
        unsigned short* Wf = wsel ? wrf : wgf;
        uint4 o;
        unsigned int s[8];
#pragma unroll
        for (int e = 0; e < 8; ++e) s[e] = f2bf(W[(size_t)(k0 + e) * OUT_C + colw]);
        o.x = s[0] | (s[1] << 16); o.y = s[2] | (s[3] << 16);
        o.z = s[4] | (s[5] << 16); o.w = s[6] | (s[7] << 16);
        reinterpret_cast<uint4*>(Wf)[u] = o;
    }

    // --- pack + store slots ---
    if (full) {
        uint2 o;
        o.x = (s0 & 0xffffu) | (s1 << 16);
        o.y = (s2 & 0xffffu) | (s3 << 16);
        *reinterpret_cast<uint2*>(slot + base) = o;
    }
}

// ---------- scan of deg (=cursor) -> per-block exclusive ptr + block sums + dinv ----------
__global__ __launch_bounds__(1024) void k_scan1(const int* __restrict__ deg, int* __restrict__ ptr,
                                                int* __restrict__ bsum, float* __restrict__ dinv, int n) {
    __shared__ int s[SCAN_BLK];
    int t = threadIdx.x;
    int i = blockIdx.x * SCAN_BLK + t;
    int v = (i < n) ? deg[i] : 0;
    s[t] = v;
    __syncthreads();
    for (int off = 1; off < SCAN_BLK; off <<= 1) {
        int add = (t >= off) ? s[t - off] : 0;
        __syncthreads();
        s[t] += add;
        __syncthreads();
    }
    if (i < n) { ptr[i] = s[t] - v; dinv[i] = rsqrtf((float)(v + 1)); }
    if (t == SCAN_BLK - 1) bsum[blockIdx.x] = s[t];
}

__global__ __launch_bounds__(64) void k_scan2(int* __restrict__ bsum, int nb) {
    __shared__ int s[64];
    int t = threadIdx.x;
    int v = (t < nb) ? bsum[t] : 0;
    s[t] = v;
    __syncthreads();
    for (int off = 1; off < 64; off <<= 1) {
        int add = (t >= off) ? s[t - off] : 0;
        __syncthreads();
        s[t] += add;
        __syncthreads();
    }
    if (t < nb) bsum[t] = s[t] - v;
}

// ---------- atomic-free CSR placement, 4 edges/thread ----------
__global__ __launch_bounds__(256) void k_place(const int* __restrict__ row,
                                               const int* __restrict__ col,
                                               const int* __restrict__ ptr,
                                               const int* __restrict__ bsum,
                                               const unsigned short* __restrict__ slot,
                                               int* __restrict__ csr_row, int E) {
    int i = blockIdx.x * 256 + threadIdx.x;
    int base = i * 4;
    if (base + 4 <= E) {
        int4 r = *reinterpret_cast<const int4*>(row + base);
        int4 c = *reinterpret_cast<const int4*>(col + base);
        uint2 sp = *reinterpret_cast<const uint2*>(slot + base);
        csr_row[ptr[c.x] + bsum[c.x >> 10] + (sp.x & 0xffffu)] = r.x;
        csr_row[ptr[c.y] + bsum[c.y >> 10] + (sp.x >> 16)]     = r.y;
        csr_row[ptr[c.z] + bsum[c.z >> 10] + (sp.y & 0xffffu)] = r.z;
        csr_row[ptr[c.w] + bsum[c.w >> 10] + (sp.y >> 16)]     = r.w;
    } else {
        for (int e = base; e < E; ++e)
            csr_row[ptr[col[e]] + bsum[col[e] >> 10] + slot[e]] = row[e];
    }
}

// ---------- fused: gather-aggregate + dual MFMA (transposed) + LN + ReLU + residual ----------
// 8 waves. Per 16-node tile: wave w gather-sums nodes {w*2, w*2+1} (per-edge dinv[r] weight),
// writes swizzled LDS agg tile; then all waves run the dual GEMM with register-resident W.
// Double-buffered LDS, 2 barriers/tile.
__global__ __launch_bounds__(512, 1) void k_aggmm(const unsigned short* __restrict__ x_bf,
                                                  const float* __restrict__ dinv,
                                                  const int* __restrict__ ptr,
                                                  const int* __restrict__ bsum,
                                                  const int* __restrict__ csr_row,
                                                  const unsigned short* __restrict__ wgf,
                                                  const unsigned short* __restrict__ wrf,
                                                  const float* __restrict__ bgc,
                                                  const float* __restrict__ gamma,
                                                  const float* __restrict__ beta,
                                                  const float* __restrict__ brc,
                                                  float* __restrict__ out,
                                                  int n, int ntiles, int E) {
    int tid = threadIdx.x;
    int w = tid >> 6, l = tid & 63;
    int g = l >> 4, lc = l & 15;

    // resident W fragments (A-operand of transposed MFMA)
    bf16x8 Wg_[2][4], Wr_[2][4];
#pragma unroll
    for (int ct2 = 0; ct2 < 2; ++ct2)
#pragma unroll
        for (int kt = 0; kt < 4; ++kt) {
            size_t idx = ((size_t)((w * 2 + ct2) * 4 + kt) * 64 + l) * 8;
            Wg_[ct2][kt] = *reinterpret_cast<const bf16x8*>(wgf + idx);
            Wr_[ct2][kt] = *reinterpret_cast<const bf16x8*>(wrf + idx);
        }

    float4 Pbg[2], Pga[2], Pbe[2], Pbr[2];
#pragma unroll
    for (int ct2 = 0; ct2 < 2; ++ct2) {
        int c0 = (w * 2 + ct2) * 16 + g * 4;
        Pbg[ct2] = *reinterpret_cast<const float4*>(bgc + c0);
        Pga[ct2] = *reinterpret_cast<const float4*>(gamma + c0);
        Pbe[ct2] = *reinterpret_cast<const float4*>(beta + c0);
        Pbr[ct2] = *reinterpret_cast<const float4*>(brc + c0);
    }

    __shared__ unsigned int atile[2][16][64];       // packed bf16x2, XOR-swizzled
    __shared__ float red1[2][8][16], red2[2][8][16];

    const unsigned int* x32 = reinterpret_cast<const unsigned int*>(x_bf);
    int buf = 0;

    for (int t = blockIdx.x; t < ntiles; t += gridDim.x) {
        // ---- Phase A: gather-aggregate 2 nodes per wave ----
#pragma unroll
        for (int sub = 0; sub < 2; ++sub) {
            int crow = w * 2 + sub;
            int c = t * 16 + crow;
            float a0 = 0.f, a1 = 0.f;
            if (c < n) {
                float dc = dinv[c];
                unsigned int p = x32[(size_t)c * 64 + l];
                a0 = bf_lo(p) * dc;                   // self-loop (×dc again at end)
                a1 = bf_hi(p) * dc;
                int e   = ptr[c] + bsum[c >> 10];
                int end = (c + 1 < n) ? (ptr[c + 1] + bsum[(c + 1) >> 10]) : E;
                for (; e + 8 <= end; e += 8) {
                    int r0 = csr_row[e],     r1 = csr_row[e + 1], r2 = csr_row[e + 2], r3 = csr_row[e + 3];
                    int r4 = csr_row[e + 4], r5 = csr_row[e + 5], r6 = csr_row[e + 6], r7 = csr_row[e + 7];
                    float w0 = dinv[r0], w1 = dinv[r1], w2 = dinv[r2], w3 = dinv[r3];
                    float w4 = dinv[r4], w5 = dinv[r5], w6 = dinv[r6], w7 = dinv[r7];
                    unsigned int q0 = x32[(size_t)r0 * 64 + l];
                    unsigned int q1 = x32[(size_t)r1 * 64 + l];
                    unsigned int q2 = x32[(size_t)r2 * 64 + l];
                    unsigned int q3 = x32[(size_t)r3 * 64 + l];
                    unsigned int q4 = x32[(size_t)r4 * 64 + l];
                    unsigned int q5 = x32[(size_t)r5 * 64 + l];
                    unsigned int q6 = x32[(size_t)r6 * 64 + l];
                    unsigned int q7 = x32[(size_t)r7 * 64 + l];
                    a0 += bf_lo(q0) * w0; a1 += bf_hi(q0) * w0;
                    a0 += bf_lo(q1) * w1; a1 += bf_hi(q1) * w1;
                    a0 += bf_lo(q2) * w2; a1 += bf_hi(q2) * w2;
                    a0 += bf_lo(q3) * w3; a1 += bf_hi(q3) * w3;
                    a0 += bf_lo(q4) * w4; a1 += bf_hi(q4) * w4;
                    a0 += bf_lo(q5) * w5; a1 += bf_hi(q5) * w5;
                    a0 += bf_lo(q6) * w6; a1 += bf_hi(q6) * w6;
                    a0 += bf_lo(q7) * w7; a1 += bf_hi(q7) * w7;
                }
                for (; e < end; ++e) {
                    int r = csr_row[e];
                    float wv = dinv[r];
                    unsigned int q = x32[(size_t)r * 64 + l];
                    a0 += bf_lo(q) * wv; a1 += bf_hi(q) * wv;
                }
                a0 *= dc; a1 *= dc;
            }
            atile[buf][crow][l ^ ((crow & 7) << 2)] = f2bf(a0) | (f2bf(a1) << 16);
        }
        __syncthreads();

        // ---- Phase B: fragments (agg from LDS swizzled, x from global) ----
        bf16x8 Fa[4], Fx[4];
        {
            int mrow = t * 16 + lc;
            if (mrow >= n) mrow = n - 1;
            const unsigned short* px = x_bf + (size_t)mrow * IN_C + g * 8;
#pragma unroll
            for (int kt = 0; kt < 4; ++kt) {
                Fx[kt] = *reinterpret_cast<const bf16x8*>(px + kt * 32);
                int j = (kt * 16 + g * 4) ^ ((lc & 7) << 2);
                Fa[kt] = *reinterpret_cast<const bf16x8*>(&atile[buf][lc][j]);
            }
        }

        f32x4 Ag[2], Ar[2];
#pragma unroll
        for (int ct2 = 0; ct2 < 2; ++ct2) {
            Ag[ct2] = (f32x4){0.f, 0.f, 0.f, 0.f};
            Ar[ct2] = (f32x4){0.f, 0.f, 0.f, 0.f};
        }
#pragma unroll
        for (int kt = 0; kt < 4; ++kt)
#pragma unroll
            for (int ct2 = 0; ct2 < 2; ++ct2) {
                Ag[ct2] = __builtin_amdgcn_mfma_f32_16x16x32_bf16(Wg_[ct2][kt], Fa[kt], Ag[ct2], 0, 0, 0);
                Ar[ct2] = __builtin_amdgcn_mfma_f32_16x16x32_bf16(Wr_[ct2][kt], Fx[kt], Ar[ct2], 0, 0, 0);
            }

        // ---- LN partials ----
        float s1 = 0.f, s2 = 0.f;
#pragma unroll
        for (int ct2 = 0; ct2 < 2; ++ct2) {
            const float* pb = reinterpret_cast<const float*>(&Pbg[ct2]);
#pragma unroll
            for (int r = 0; r < 4; ++r) {
                float v = Ag[ct2][r] + pb[r];
                Ag[ct2][r] = v;
                s1 += v; s2 += v * v;
            }
        }
        s1 += __shfl_xor(s1, 16); s2 += __shfl_xor(s2, 16);
        s1 += __shfl_xor(s1, 32); s2 += __shfl_xor(s2, 32);

        if (l < 16) { red1[buf][w][lc] = s1; red2[buf][w][lc] = s2; }
        __syncthreads();

        float u1 = 0.f, u2 = 0.f;
#pragma unroll
        for (int wv = 0; wv < 8; ++wv) {
            u1 += red1[buf][wv][lc];
            u2 += red2[buf][wv][lc];
        }
        float mu  = u1 * (1.f / OUT_C);
        float var = u2 * (1.f / OUT_C) - mu * mu;
        float rs  = rsqrtf(var + LN_EPS);

        // ---- epilogue: dwordx4 stores ----
        int rown = t * 16 + lc;
        if (rown < n) {
#pragma unroll
            for (int ct2 = 0; ct2 < 2; ++ct2) {
                const float* pg = reinterpret_cast<const float*>(&Pga[ct2]);
                const float* pe = reinterpret_cast<const float*>(&Pbe[ct2]);
                const float* pr = reinterpret_cast<const float*>(&Pbr[ct2]);
                f32x4 o;
#pragma unroll
                for (int r = 0; r < 4; ++r) {
                    float ln = (Ag[ct2][r] - mu) * rs * pg[r] + pe[r];
                    o[r] = fmaxf(ln, 0.f) + Ar[ct2][r] + pr[r];
                }
                *reinterpret_cast<f32x4*>(out + (size_t)rown * OUT_C + (w * 2 + ct2) * 16 + g * 4) = o;
            }
        }
        buf ^= 1;   // no trailing barrier needed: next gather writes the other buffer
    }
}

extern "C" void kernel_launch(void* const* d_in, const int* in_sizes, int n_in,
                              void* d_out, int out_size, void* d_ws, size_t ws_size,
                              hipStream_t stream) {
    const float* x     = (const float*)d_in[0];
    const int*   ei    = (const int*)d_in[1];
    const float* Wg    = (const float*)d_in[2];
    const float* bg    = (const float*)d_in[3];
    const float* gamma = (const float*)d_in[4];
    const float* beta  = (const float*)d_in[5];
    const float* Wr    = (const float*)d_in[6];
    const float* br    = (const float*)d_in[7];
    float* out = (float*)d_out;

    int N = in_sizes[0] / IN_C;
    int E = in_sizes[1] / 2;
    const int* row = ei;
    const int* col = ei + E;

    char* ws = (char*)d_ws;
    size_t off = 0;
    auto alloc = [&](size_t bytes) -> void* {
        void* p = ws + off;
        off += (bytes + 255) & ~(size_t)255;
        return p;
    };
    unsigned short* x_bf = (unsigned short*)alloc((size_t)N * IN_C * 2);
    unsigned short* wgf  = (unsigned short*)alloc((size_t)IN_C * OUT_C * 2);
    unsigned short* wrf  = (unsigned short*)alloc((size_t)IN_C * OUT_C * 2);
    float* dinv    = (float*)alloc((size_t)N * sizeof(float));
    int*   cursor  = (int*)alloc((size_t)N * sizeof(int));   // becomes deg
    int*   ptr     = (int*)alloc((size_t)N * sizeof(int));
    int*   bsum    = (int*)alloc(64 * sizeof(int));
    unsigned short* slot = (unsigned short*)alloc((size_t)E * sizeof(unsigned short));
    int*   csr_row = (int*)alloc((size_t)E * sizeof(int));
    (void)ws_size; (void)n_in; (void)out_size;

    int nsb  = (N + SCAN_BLK - 1) / SCAN_BLK;            // 49
    int ncvt = N * (IN_C / 32);                           // 200000 convert threads
    int nbig = ((E + 3) / 4 > ncvt ? (E + 3) / 4 : ncvt);
    int nbF  = (nbig + 255) / 256;
    int nbE4 = (E + 1023) / 1024;
    int ntiles = (N + 15) / 16;
    int ngrid  = ntiles < 512 ? ntiles : 512;
    int n4     = (N + 3) / 4;

    k_zero   <<<(n4 + 255) / 256, 256, 0, stream>>>((int4*)cursor, n4);
    k_slotcvt<<<nbF, 256, 0, stream>>>(col, cursor, slot, x, x_bf, Wg, Wr, wgf, wrf, E, ncvt);
    k_scan1  <<<nsb, 1024, 0, stream>>>(cursor, ptr, bsum, dinv, N);
    k_scan2  <<<1, 64, 0, stream>>>(bsum, nsb);
    k_place  <<<nbE4, 256, 0, stream>>>(row, col, ptr, bsum, slot, csr_row, E);
    k_aggmm  <<<ngrid, 512, 0, stream>>>(x_bf, dinv, ptr, bsum, csr_row, wgf, wrf,
                                         bg, gamma, beta, br, out, N, ntiles, E);
}

// Round 10
// 147.460 us; speedup vs baseline: 1.3548x; 1.3548x over previous
//
#include <hip/hip_runtime.h>

#define IN_C 128
#define OUT_C 256
#define LN_EPS 1e-5f
#define SCAN_BLK 1024

typedef __attribute__((ext_vector_type(8))) short bf16x8;
typedef __attribute__((ext_vector_type(4))) float f32x4;

__device__ __forceinline__ unsigned int f2bf(float f) {
    unsigned int u = __float_as_uint(f);
    return (u + 0x7fffu + ((u >> 16) & 1u)) >> 16;   // RNE
}
__device__ __forceinline__ float bf_lo(unsigned int p) { return __uint_as_float(p << 16); }
__device__ __forceinline__ float bf_hi(unsigned int p) { return __uint_as_float(p & 0xffff0000u); }

// ---------- zero 4-replica cursor ----------
__global__ __launch_bounds__(256) void k_zero(int4* __restrict__ p, int n4) {
    int i = blockIdx.x * 256 + threadIdx.x;
    if (i < n4) p[i] = (int4){0, 0, 0, 0};
}

// ---------- fused: slot reservation (4-replica atomics) + x->bf16 + weight fragments ----------
// Replica = edge_index & 3: per-node atomic chains shrink 4x; a thread's 4 atomics hit 4 replicas.
__global__ __launch_bounds__(256) void k_slotcvt(const int* __restrict__ col,
                                                 int* __restrict__ cursor,
                                                 unsigned short* __restrict__ slot,
                                                 const float* __restrict__ x,
                                                 unsigned short* __restrict__ x_bf,
                                                 const float* __restrict__ Wg,
                                                 const float* __restrict__ Wr,
                                                 unsigned short* __restrict__ wgf,
                                                 unsigned short* __restrict__ wrf,
                                                 int E, int ncvt, int N) {
    int i = blockIdx.x * 256 + threadIdx.x;

    int base = i * 4;
    unsigned int s0, s1, s2, s3;
    bool full = (base + 4 <= E);
    if (full) {
        int4 c = *reinterpret_cast<const int4*>(col + base);
        s0 = (unsigned int)atomicAdd(&cursor[0 * N + c.x], 1);
        s1 = (unsigned int)atomicAdd(&cursor[1 * N + c.y], 1);
        s2 = (unsigned int)atomicAdd(&cursor[2 * N + c.z], 1);
        s3 = (unsigned int)atomicAdd(&cursor[3 * N + c.w], 1);
    } else {
        for (int e = base; e < E; ++e)
            slot[e] = (unsigned short)atomicAdd(&cursor[(e & 3) * N + col[e]], 1);
    }

    // --- x -> bf16 (unscaled), 32 floats/thread; rides under atomic latency ---
    if (i < ncvt) {
        const float4* xv = reinterpret_cast<const float4*>(x) + (size_t)i * 8;
        uint4* dst = reinterpret_cast<uint4*>(x_bf) + (size_t)i * 4;
#pragma unroll
        for (int j = 0; j < 4; ++j) {
            float4 a = xv[j * 2], b = xv[j * 2 + 1];
            uint4 o;
            o.x = f2bf(a.x) | (f2bf(a.y) << 16);
            o.y = f2bf(a.z) | (f2bf(a.w) << 16);
            o.z = f2bf(b.x) | (f2bf(b.y) << 16);
            o.w = f2bf(b.z) | (f2bf(b.w) << 16);
            dst[j] = o;
        }
    }

    // --- weight fragments (first 8192 threads) ---
    if (i < 8192) {
        int wsel = i >> 12;
        int u = i & 4095;
        int ct = u >> 8, kt = (u >> 6) & 3, l = u & 63;
        int k0 = kt * 32 + (l >> 4) * 8;
        int colw = ct * 16 + (l & 15);
        const float* W = wsel ? Wr : Wg;
        unsigned short* Wf = wsel ? wrf : wgf;
        uint4 o;
        unsigned int s[8];
#pragma unroll
        for (int e = 0; e < 8; ++e) s[e] = f2bf(W[(size_t)(k0 + e) * OUT_C + colw]);
        o.x = s[0] | (s[1] << 16); o.y = s[2] | (s[3] << 16);
        o.z = s[4] | (s[5] << 16); o.w = s[6] | (s[7] << 16);
        reinterpret_cast<uint4*>(Wf)[u] = o;
    }

    if (full) {
        uint2 o;
        o.x = (s0 & 0xffffu) | (s1 << 16);
        o.y = (s2 & 0xffffu) | (s3 << 16);
        *reinterpret_cast<uint2*>(slot + base) = o;
    }
}

// ---------- scan: deg = sum of 4 replicas; write back per-replica exclusive bases ----------
__global__ __launch_bounds__(1024) void k_scan1(int* __restrict__ cur, int* __restrict__ ptr,
                                                int* __restrict__ bsum, float* __restrict__ dinv,
                                                int n) {
    __shared__ int s[SCAN_BLK];
    int t = threadIdx.x;
    int i = blockIdx.x * SCAN_BLK + t;
    int r0 = 0, r1 = 0, r2 = 0, r3 = 0;
    if (i < n) {
        r0 = cur[i]; r1 = cur[n + i]; r2 = cur[2 * n + i]; r3 = cur[3 * n + i];
    }
    int v = r0 + r1 + r2 + r3;
    s[t] = v;
    __syncthreads();
    for (int off = 1; off < SCAN_BLK; off <<= 1) {
        int add = (t >= off) ? s[t - off] : 0;
        __syncthreads();
        s[t] += add;
        __syncthreads();
    }
    if (i < n) {
        ptr[i] = s[t] - v;
        dinv[i] = rsqrtf((float)(v + 1));
        cur[i] = 0;
        cur[n + i] = r0;
        cur[2 * n + i] = r0 + r1;
        cur[3 * n + i] = r0 + r1 + r2;
    }
    if (t == SCAN_BLK - 1) bsum[blockIdx.x] = s[t];
}

__global__ __launch_bounds__(64) void k_scan2(int* __restrict__ bsum, int nb) {
    __shared__ int s[64];
    int t = threadIdx.x;
    int v = (t < nb) ? bsum[t] : 0;
    s[t] = v;
    __syncthreads();
    for (int off = 1; off < 64; off <<= 1) {
        int add = (t >= off) ? s[t - off] : 0;
        __syncthreads();
        s[t] += add;
        __syncthreads();
    }
    if (t < nb) bsum[t] = s[t] - v;
}

// ---------- fused: atomic-free CSR placement (replica bases) + xs convert from x_bf ----------
__global__ __launch_bounds__(256) void k_placecvt(const int* __restrict__ row,
                                                  const int* __restrict__ col,
                                                  const int* __restrict__ ptr,
                                                  const int* __restrict__ bsum,
                                                  const int* __restrict__ cur,
                                                  const unsigned short* __restrict__ slot,
                                                  int* __restrict__ csr_row,
                                                  const unsigned short* __restrict__ x_bf,
                                                  const float* __restrict__ dinv,
                                                  unsigned short* __restrict__ xs_bf,
                                                  int E, int ncvt, int N) {
    int i = blockIdx.x * 256 + threadIdx.x;

    int base = i * 4;
    if (base + 4 <= E) {
        int4 r = *reinterpret_cast<const int4*>(row + base);
        int4 c = *reinterpret_cast<const int4*>(col + base);
        uint2 sp = *reinterpret_cast<const uint2*>(slot + base);
        csr_row[ptr[c.x] + bsum[c.x >> 10] + cur[0 * N + c.x] + (sp.x & 0xffffu)] = r.x;
        csr_row[ptr[c.y] + bsum[c.y >> 10] + cur[1 * N + c.y] + (sp.x >> 16)]     = r.y;
        csr_row[ptr[c.z] + bsum[c.z >> 10] + cur[2 * N + c.z] + (sp.y & 0xffffu)] = r.z;
        csr_row[ptr[c.w] + bsum[c.w >> 10] + cur[3 * N + c.w] + (sp.y >> 16)]     = r.w;
    } else {
        for (int e = base; e < E; ++e) {
            int c = col[e];
            csr_row[ptr[c] + bsum[c >> 10] + cur[(e & 3) * N + c] + slot[e]] = row[e];
        }
    }

    // --- xs = dinv * x_bf -> bf16, 32 elems/thread (quarter-row) ---
    if (i < ncvt) {
        float dn = dinv[i >> 2];
        const uint4* xv = reinterpret_cast<const uint4*>(x_bf) + (size_t)i * 4;
        uint4* dst = reinterpret_cast<uint4*>(xs_bf) + (size_t)i * 4;
#pragma unroll
        for (int j = 0; j < 4; ++j) {
            uint4 u = xv[j];
            uint4 o;
            o.x = f2bf(bf_lo(u.x) * dn) | (f2bf(bf_hi(u.x) * dn) << 16);
            o.y = f2bf(bf_lo(u.y) * dn) | (f2bf(bf_hi(u.y) * dn) << 16);
            o.z = f2bf(bf_lo(u.z) * dn) | (f2bf(bf_hi(u.z) * dn) << 16);
            o.w = f2bf(bf_lo(u.w) * dn) | (f2bf(bf_hi(u.w) * dn) << 16);
            dst[j] = o;
        }
    }
}

// ---------- aggregation: agg[c] = dinv[c] * (xs[c] + sum_e xs[r]), unroll x8 ----------
__global__ __launch_bounds__(256) void k_agg(const unsigned int* __restrict__ xs32,
                                             const float* __restrict__ dinv,
                                             const int* __restrict__ ptr,
                                             const int* __restrict__ bsum,
                                             const int* __restrict__ csr_row,
                                             unsigned short* __restrict__ agg_bf, int n, int E) {
    int c = blockIdx.x * 4 + (threadIdx.x >> 6);
    if (c >= n) return;
    int lane = threadIdx.x & 63;
    float dc = dinv[c];
    unsigned int p = xs32[(size_t)c * 64 + lane];
    float a0 = bf_lo(p), a1 = bf_hi(p);
    int e   = ptr[c] + bsum[c >> 10];
    int end = (c + 1 < n) ? (ptr[c + 1] + bsum[(c + 1) >> 10]) : E;
    for (; e + 8 <= end; e += 8) {
        int r0 = csr_row[e],     r1 = csr_row[e + 1], r2 = csr_row[e + 2], r3 = csr_row[e + 3];
        int r4 = csr_row[e + 4], r5 = csr_row[e + 5], r6 = csr_row[e + 6], r7 = csr_row[e + 7];
        unsigned int q0 = xs32[(size_t)r0 * 64 + lane];
        unsigned int q1 = xs32[(size_t)r1 * 64 + lane];
        unsigned int q2 = xs32[(size_t)r2 * 64 + lane];
        unsigned int q3 = xs32[(size_t)r3 * 64 + lane];
        unsigned int q4 = xs32[(size_t)r4 * 64 + lane];
        unsigned int q5 = xs32[(size_t)r5 * 64 + lane];
        unsigned int q6 = xs32[(size_t)r6 * 64 + lane];
        unsigned int q7 = xs32[(size_t)r7 * 64 + lane];
        a0 += bf_lo(q0); a1 += bf_hi(q0);
        a0 += bf_lo(q1); a1 += bf_hi(q1);
        a0 += bf_lo(q2); a1 += bf_hi(q2);
        a0 += bf_lo(q3); a1 += bf_hi(q3);
        a0 += bf_lo(q4); a1 += bf_hi(q4);
        a0 += bf_lo(q5); a1 += bf_hi(q5);
        a0 += bf_lo(q6); a1 += bf_hi(q6);
        a0 += bf_lo(q7); a1 += bf_hi(q7);
    }
    for (; e < end; ++e) {
        unsigned int q = xs32[(size_t)csr_row[e] * 64 + lane];
        a0 += bf_lo(q); a1 += bf_hi(q);
    }
    a0 *= dc; a1 *= dc;
    *reinterpret_cast<unsigned int*>(agg_bf + (size_t)c * IN_C + lane * 2) = f2bf(a0) | (f2bf(a1) << 16);
}

// ---------- fused MFMA dual-GEMM (transposed output) + LN + ReLU + residual ----------
__global__ __launch_bounds__(512, 2) void k_mfma(const unsigned short* __restrict__ agg_bf,
                                                 const unsigned short* __restrict__ x_bf,
                                                 const unsigned short* __restrict__ wgf,
                                                 const unsigned short* __restrict__ wrf,
                                                 const float* __restrict__ bgc,
                                                 const float* __restrict__ gamma,
                                                 const float* __restrict__ beta,
                                                 const float* __restrict__ brc,
                                                 float* __restrict__ out, int n, int ntiles, int chunk) {
    int tid = threadIdx.x;
    int w = tid >> 6, l = tid & 63;
    int g = l >> 4, lc = l & 15;

    int t0 = blockIdx.x * chunk;
    int tend = t0 + chunk;
    if (tend > ntiles) tend = ntiles;
    if (t0 >= tend) return;

    bf16x8 Wgf[2][4], Wrf[2][4];
#pragma unroll
    for (int ct2 = 0; ct2 < 2; ++ct2)
#pragma unroll
        for (int kt = 0; kt < 4; ++kt) {
            size_t idx = ((size_t)((w * 2 + ct2) * 4 + kt) * 64 + l) * 8;
            Wgf[ct2][kt] = *reinterpret_cast<const bf16x8*>(wgf + idx);
            Wrf[ct2][kt] = *reinterpret_cast<const bf16x8*>(wrf + idx);
        }

    float4 Pbg[2], Pga[2], Pbe[2], Pbr[2];
#pragma unroll
    for (int ct2 = 0; ct2 < 2; ++ct2) {
        int c0 = (w * 2 + ct2) * 16 + g * 4;
        Pbg[ct2] = *reinterpret_cast<const float4*>(bgc + c0);
        Pga[ct2] = *reinterpret_cast<const float4*>(gamma + c0);
        Pbe[ct2] = *reinterpret_cast<const float4*>(beta + c0);
        Pbr[ct2] = *reinterpret_cast<const float4*>(brc + c0);
    }

    __shared__ float red1[2][8][16], red2[2][8][16];

    bf16x8 Fa[4], Fx[4];
    {
        int mrow = t0 * 16 + lc;
        if (mrow >= n) mrow = n - 1;
        const unsigned short* pa = agg_bf + (size_t)mrow * IN_C + g * 8;
        const unsigned short* px = x_bf   + (size_t)mrow * IN_C + g * 8;
#pragma unroll
        for (int kt = 0; kt < 4; ++kt) {
            Fa[kt] = *reinterpret_cast<const bf16x8*>(pa + kt * 32);
            Fx[kt] = *reinterpret_cast<const bf16x8*>(px + kt * 32);
        }
    }

    for (int t = t0; t < tend; ++t) {
        f32x4 Ag[2], Ar[2];
#pragma unroll
        for (int ct2 = 0; ct2 < 2; ++ct2) {
            Ag[ct2] = (f32x4){0.f, 0.f, 0.f, 0.f};
            Ar[ct2] = (f32x4){0.f, 0.f, 0.f, 0.f};
        }

#pragma unroll
        for (int kt = 0; kt < 4; ++kt)
#pragma unroll
            for (int ct2 = 0; ct2 < 2; ++ct2) {
                Ag[ct2] = __builtin_amdgcn_mfma_f32_16x16x32_bf16(Wgf[ct2][kt], Fa[kt], Ag[ct2], 0, 0, 0);
                Ar[ct2] = __builtin_amdgcn_mfma_f32_16x16x32_bf16(Wrf[ct2][kt], Fx[kt], Ar[ct2], 0, 0, 0);
            }

        {
            int tn = (t + 1 < tend) ? t + 1 : t;
            int mrow = tn * 16 + lc;
            if (mrow >= n) mrow = n - 1;
            const unsigned short* pa = agg_bf + (size_t)mrow * IN_C + g * 8;
            const unsigned short* px = x_bf   + (size_t)mrow * IN_C + g * 8;
#pragma unroll
            for (int kt = 0; kt < 4; ++kt) {
                Fa[kt] = *reinterpret_cast<const bf16x8*>(pa + kt * 32);
                Fx[kt] = *reinterpret_cast<const bf16x8*>(px + kt * 32);
            }
        }

        float s1 = 0.f, s2 = 0.f;
#pragma unroll
        for (int ct2 = 0; ct2 < 2; ++ct2) {
            const float* pb = reinterpret_cast<const float*>(&Pbg[ct2]);
#pragma unroll
            for (int r = 0; r < 4; ++r) {
                float v = Ag[ct2][r] + pb[r];
                Ag[ct2][r] = v;
                s1 += v; s2 += v * v;
            }
        }
        s1 += __shfl_xor(s1, 16); s2 += __shfl_xor(s2, 16);
        s1 += __shfl_xor(s1, 32); s2 += __shfl_xor(s2, 32);

        int buf = t & 1;
        if (l < 16) { red1[buf][w][lc] = s1; red2[buf][w][lc] = s2; }
        __syncthreads();

        float u1 = 0.f, u2 = 0.f;
#pragma unroll
        for (int wv = 0; wv < 8; ++wv) {
            u1 += red1[buf][wv][lc];
            u2 += red2[buf][wv][lc];
        }
        float mu  = u1 * (1.f / OUT_C);
        float var = u2 * (1.f / OUT_C) - mu * mu;
        float rs  = rsqrtf(var + LN_EPS);

        int rown = t * 16 + lc;
        if (rown < n) {
#pragma unroll
            for (int ct2 = 0; ct2 < 2; ++ct2) {
                const float* pg = reinterpret_cast<const float*>(&Pga[ct2]);
                const float* pe = reinterpret_cast<const float*>(&Pbe[ct2]);
                const float* pr = reinterpret_cast<const float*>(&Pbr[ct2]);
                f32x4 o;
#pragma unroll
                for (int r = 0; r < 4; ++r) {
                    float ln = (Ag[ct2][r] - mu) * rs * pg[r] + pe[r];
                    o[r] = fmaxf(ln, 0.f) + Ar[ct2][r] + pr[r];
                }
                *reinterpret_cast<f32x4*>(out + (size_t)rown * OUT_C + (w * 2 + ct2) * 16 + g * 4) = o;
            }
        }
    }
}

extern "C" void kernel_launch(void* const* d_in, const int* in_sizes, int n_in,
                              void* d_out, int out_size, void* d_ws, size_t ws_size,
                              hipStream_t stream) {
    const float* x     = (const float*)d_in[0];
    const int*   ei    = (const int*)d_in[1];
    const float* Wg    = (const float*)d_in[2];
    const float* bg    = (const float*)d_in[3];
    const float* gamma = (const float*)d_in[4];
    const float* beta  = (const float*)d_in[5];
    const float* Wr    = (const float*)d_in[6];
    const float* br    = (const float*)d_in[7];
    float* out = (float*)d_out;

    int N = in_sizes[0] / IN_C;
    int E = in_sizes[1] / 2;
    const int* row = ei;
    const int* col = ei + E;

    char* ws = (char*)d_ws;
    size_t off = 0;
    auto alloc = [&](size_t bytes) -> void* {
        void* p = ws + off;
        off += (bytes + 255) & ~(size_t)255;
        return p;
    };
    unsigned short* x_bf   = (unsigned short*)alloc((size_t)N * IN_C * 2);
    unsigned short* xs_bf  = (unsigned short*)alloc((size_t)N * IN_C * 2);
    unsigned short* agg_bf = (unsigned short*)alloc((size_t)N * IN_C * 2);
    unsigned short* wgf    = (unsigned short*)alloc((size_t)IN_C * OUT_C * 2);
    unsigned short* wrf    = (unsigned short*)alloc((size_t)IN_C * OUT_C * 2);
    float* dinv    = (float*)alloc((size_t)N * sizeof(float));
    int*   cursor  = (int*)alloc((size_t)4 * N * sizeof(int));  // 4 replicas; becomes per-replica bases
    int*   ptr     = (int*)alloc((size_t)N * sizeof(int));
    int*   bsum    = (int*)alloc(64 * sizeof(int));
    unsigned short* slot = (unsigned short*)alloc((size_t)E * sizeof(unsigned short));
    int*   csr_row = (int*)alloc((size_t)E * sizeof(int));
    (void)ws_size; (void)n_in; (void)out_size;

    int nsb  = (N + SCAN_BLK - 1) / SCAN_BLK;            // 49
    int ncvt = N * (IN_C / 32);                           // 200000
    int nbig = ((E + 3) / 4 > ncvt ? (E + 3) / 4 : ncvt);
    int nbF  = (nbig + 255) / 256;
    int ntiles = (N + 15) / 16;
    int ngrid  = 256;
    int chunk  = (ntiles + ngrid - 1) / ngrid;
    int n4     = N;   // 4N ints = N int4s

    k_zero    <<<(n4 + 255) / 256, 256, 0, stream>>>((int4*)cursor, n4);
    k_slotcvt <<<nbF, 256, 0, stream>>>(col, cursor, slot, x, x_bf, Wg, Wr, wgf, wrf, E, ncvt, N);
    k_scan1   <<<nsb, 1024, 0, stream>>>(cursor, ptr, bsum, dinv, N);
    k_scan2   <<<1, 64, 0, stream>>>(bsum, nsb);
    k_placecvt<<<nbF, 256, 0, stream>>>(row, col, ptr, bsum, cursor, slot, csr_row,
                                        x_bf, dinv, xs_bf, E, ncvt, N);
    k_agg     <<<(N + 3) / 4, 256, 0, stream>>>((const unsigned int*)xs_bf, dinv, ptr, bsum,
                                                csr_row, agg_bf, N, E);
    k_mfma    <<<ngrid, 512, 0, stream>>>(agg_bf, x_bf, wgf, wrf, bg, gamma, beta, br,
                                          out, N, ntiles, chunk);
}